// Round 1
// baseline (56.902 us; speedup 1.0000x reference)
//
#include <hip/hip_runtime.h>
#include <math.h>

#define NVOICE 8
#define NPROF  16
#define NHARM  64
#define NFRAME 64
#define NSAMP  16384
#define NROWPV 65                       // 1 fundamental + 64 harmonics
#define NROWS  (NVOICE * NROWPV)        // 520 rows per batch
#define NB     16

// MIN_FREQ = FREQ_INTERVAL = 40 / 11025
__device__ __forceinline__ float min_freq() { return 40.0f / 11025.0f; }

// ---------------------------------------------------------------------------
// Phase A: per (b, v, frame) compute frame-rate freq/amp for all 65 rows,
// then per-row frame prefix sums of the cumsum (stored mod 2, computed in f64).
//
// ws layout (floats):
//   F[b][frame][row]  : NB*NFRAME*NROWS
//   A[b][frame][row]  : NB*NFRAME*NROWS
//   P[b][k][row]      : NB*NFRAME*NROWS   (prefix BEFORE segment k, mod 2)
// ---------------------------------------------------------------------------
__global__ __launch_bounds__(64)
void hm_phaseA(const float* __restrict__ f0,
               const float* __restrict__ harm,
               const float* __restrict__ prof,
               float* __restrict__ Fws,
               float* __restrict__ Aws,
               float* __restrict__ Pws)
{
    const int blk = blockIdx.x;          // 0..127 = b*8 + v
    const int b = blk >> 3, v = blk & 7;
    const int f = threadIdx.x;           // frame 0..63

    __shared__ float profl[NPROF * NHARM];   // 4 KB
    __shared__ float Fl[NROWPV][NFRAME];     // 16.6 KB (freqs for prefix pass)

    for (int t = f; t < NPROF * NHARM; t += 64) profl[t] = prof[t];

    const float re   = f0[((size_t)b * 16 + 2 * v    ) * NFRAME + f];
    const float im   = f0[((size_t)b * 16 + 2 * v + 1) * NFRAME + f];
    const float amp0 = re * re + im * im;
    const float ang  = atan2f(im, re) * 0.3183098861837907f;  // /pi
    const float base = min_freq() + ang * ang * min_freq();

    // softmax over 16 profiles for this (b,v,f)
    float w[NPROF];
    float m = -INFINITY;
#pragma unroll
    for (int p = 0; p < NPROF; ++p) {
        w[p] = harm[((size_t)b * (NVOICE * NPROF) + v * NPROF + p) * NFRAME + f];
        m = fmaxf(m, w[p]);
    }
    float s = 0.0f;
#pragma unroll
    for (int p = 0; p < NPROF; ++p) { w[p] = expf(w[p] - m); s += w[p]; }
    const float inv = 1.0f / s;
#pragma unroll
    for (int p = 0; p < NPROF; ++p) w[p] *= inv;

    __syncthreads();   // profl ready

    const int rowbase = v * NROWPV;
    float* Fo = Fws + ((size_t)b * NFRAME + f) * NROWS + rowbase;
    float* Ao = Aws + ((size_t)b * NFRAME + f) * NROWS + rowbase;

    // row 0: fundamental
    Fo[0] = base; Ao[0] = amp0; Fl[0][f] = base;

    // rows 1..64: harmonics; ratio = (h+1)^2  (RATIOS[h-1] = ((h-1)+2)^2)
    for (int h = 1; h <= NHARM; ++h) {
        const float r  = (float)((h + 1) * (h + 1));
        const float Fv = fminf(base * r, 1.0f);       // clip(.,0,1); base>0
        float ha = 0.0f;
#pragma unroll
        for (int p = 0; p < NPROF; ++p) ha = fmaf(w[p], profl[p * NHARM + (h - 1)], ha);
        ha = fminf(fmaxf(ha, 0.0f), 1.0f) * amp0;
        Fo[h] = Fv; Ao[h] = ha; Fl[h][f] = Fv;
    }
    __syncthreads();

    // prefix pass: each thread walks whole rows sequentially (64 frames), f64.
    // P_0 = 128*F_0 (flat head); P_{k} = P_{k-1} + 128*(F_{k-1}+F_k).
    for (int h = f; h < NROWPV; h += 64) {
        double p = 128.0 * (double)Fl[h][0];
        Pws[((size_t)b * NFRAME + 0) * NROWS + rowbase + h] =
            (float)(p - 2.0 * floor(p * 0.5));
        float prev = Fl[h][0];
        for (int k = 1; k < NFRAME; ++k) {
            const float cur = Fl[h][k];
            p += 128.0 * ((double)prev + (double)cur);
            Pws[((size_t)b * NFRAME + k) * NROWS + rowbase + h] =
                (float)(p - 2.0 * floor(p * 0.5));
            prev = cur;
        }
    }
}

// ---------------------------------------------------------------------------
// Phase B: one block per (batch, 256-sample chunk). Thread = one sample.
// Low half-block (tid<128) lies in segment c-1, high half in segment c.
//   S(i)  = P_k + t1*F_k + t2*(F_{k+1}-F_k),  t1=j+1, t2=(j+1)^2/512
//   fa(i) = A_k + t3*(A_{k+1}-A_k),           t3=(j+0.5)/256
// Head (c==0, low): P=0 (zeroed in LDS), t1=i+1, dF=dA=0 automatically.
// Tail (c==63, high): t1=i-16255, frame clamped so dF=dA=0.
// sin(pi*S) = v_sin_f32(fract(S/2))  [v_sin takes revolutions]
// ---------------------------------------------------------------------------
__global__ __launch_bounds__(256)
void hm_phaseB(const float* __restrict__ Fws,
               const float* __restrict__ Aws,
               const float* __restrict__ Pws,
               float* __restrict__ out)
{
    const int blk = blockIdx.x;          // 0..1023
    const int b   = blk >> 6;
    const int c   = blk & 63;
    const int tid = threadIdx.x;

    __shared__ float4 lo4[NROWS], hi4[NROWS];   // {F, dF, A, dA}
    __shared__ float  plo[NROWS], phi[NROWS];

    const int fm1 = (c > 0)  ? c - 1 : 0;
    const int fp1 = (c < 63) ? c + 1 : 63;
    const float* Fb = Fws + (size_t)b * NFRAME * NROWS;
    const float* Ab = Aws + (size_t)b * NFRAME * NROWS;
    const float* Pb = Pws + (size_t)b * NFRAME * NROWS;

    for (int r = tid; r < NROWS; r += 256) {
        const float Fm = Fb[(size_t)fm1 * NROWS + r];
        const float Fc = Fb[(size_t)c   * NROWS + r];
        const float Fp = Fb[(size_t)fp1 * NROWS + r];
        const float Am = Ab[(size_t)fm1 * NROWS + r];
        const float Ac = Ab[(size_t)c   * NROWS + r];
        const float Ap = Ab[(size_t)fp1 * NROWS + r];
        lo4[r] = make_float4(Fm, Fc - Fm, Am, Ac - Am);
        hi4[r] = make_float4(Fc, Fp - Fc, Ac, Ap - Ac);
        plo[r] = (c == 0) ? 0.0f : Pb[(size_t)(c - 1) * NROWS + r];
        phi[r] = Pb[(size_t)c * NROWS + r];
    }
    __syncthreads();

    const bool low = (tid < 128);
    const int  j   = (tid + 128) & 255;       // in-segment sample index
    float t1 = (float)(j + 1);
    const float t2 = (float)((j + 1) * (j + 1)) * (1.0f / 512.0f);
    const float t3 = ((float)j + 0.5f) * (1.0f / 256.0f);
    if (c == 0  && low)  t1 = (float)(tid + 1);     // flat head: S=(i+1)*F0
    if (c == 63 && !low) t1 = (float)(tid - 127);   // flat tail: S=P63+(i-16255)*F63

    const float4* V = low ? lo4 : hi4;
    const float*  P = low ? plo : phi;

    float acc = 0.0f;
#pragma unroll 4
    for (int r = 0; r < NROWS; ++r) {
        const float4 vv = V[r];
        const float S  = fmaf(t2, vv.y, fmaf(t1, vv.x, P[r]));
        const float fa = fmaf(t3, vv.w, vv.z);
        const float x  = 0.5f * S;
        const float fr = x - floorf(x);                 // S/2 in revolutions
        acc = fmaf(fa, __builtin_amdgcn_sinf(fr), acc); // sin(2*pi*fr)=sin(pi*S)
    }

    out[(size_t)b * NSAMP + c * 256 + tid] = acc;
}

// ---------------------------------------------------------------------------
extern "C" void kernel_launch(void* const* d_in, const int* in_sizes, int n_in,
                              void* d_out, int out_size, void* d_ws, size_t ws_size,
                              hipStream_t stream)
{
    const float* f0   = (const float*)d_in[0];   // (16, 16, 64)
    const float* harm = (const float*)d_in[1];   // (16, 128, 64)
    const float* prof = (const float*)d_in[2];   // (16, 64)

    const size_t plane = (size_t)NB * NFRAME * NROWS;   // 532480 floats
    float* Fws = (float*)d_ws;
    float* Aws = Fws + plane;
    float* Pws = Aws + plane;

    hm_phaseA<<<NB * NVOICE, 64, 0, stream>>>(f0, harm, prof, Fws, Aws, Pws);
    hm_phaseB<<<NB * (NSAMP / 256), 256, 0, stream>>>(Fws, Aws, Pws, (float*)d_out);
}

// Round 2
// 21.199 us; speedup vs baseline: 2.6841x; 2.6841x over previous
//
#include <hip/hip_runtime.h>
#include <math.h>

#define NVOICE 8
#define NPROF  16
#define NHARM  64
#define NFRAME 64
#define NSAMP  16384
#define NB     16

// Only harmonics h in [0,15] can ever have freq < 1.0.  For h >= 16,
// base*(h+1)^2 >= MIN_FREQ*289 = 1.048 > 1 for every frame, so freq
// clips to exactly 1.0, the phase prefix is an even integer, S is an
// integer, and sin(pi*S) == 0 exactly: those rows contribute nothing.
#define NKEEP  16
#define NROWS2 (NVOICE * NKEEP)        // 128 rows per batch

// MIN_FREQ = FREQ_INTERVAL = 40 / 11025
__device__ __forceinline__ float min_freq() { return 40.0f / 11025.0f; }

// ---------------------------------------------------------------------------
// Phase A: per (b, v, frame) compute frame-rate freq/amp for rows h=0..15,
// then per-row frame prefix of the cumsum, all stored HALVED:
//   Fws: F/2 per frame, Aws: amplitude, Pws: (prefix/2) mod 1  (f64 exact)
// ws layout (floats): X[b][frame][row], row = v*16 + h, NROWS2=128 rows.
// ---------------------------------------------------------------------------
__global__ __launch_bounds__(64)
void hm_phaseA(const float* __restrict__ f0,
               const float* __restrict__ harm,
               const float* __restrict__ prof,
               float* __restrict__ Fws,
               float* __restrict__ Aws,
               float* __restrict__ Pws)
{
    const int blk = blockIdx.x;          // 0..127 = b*8 + v
    const int b = blk >> 3, v = blk & 7;
    const int f = threadIdx.x;           // frame 0..63

    __shared__ float profl[NPROF][NKEEP];   // columns h-1 = 0..14 used
    __shared__ float Fl[NKEEP][NFRAME];     // unhalved freqs for prefix pass

    for (int t = f; t < NPROF * NKEEP; t += 64) {
        const int p = t >> 4, c = t & 15;
        profl[p][c] = prof[p * NHARM + c];
    }

    const float re   = f0[((size_t)b * 16 + 2 * v    ) * NFRAME + f];
    const float im   = f0[((size_t)b * 16 + 2 * v + 1) * NFRAME + f];
    const float amp0 = re * re + im * im;
    const float ang  = atan2f(im, re) * 0.3183098861837907f;  // /pi
    const float base = min_freq() + ang * ang * min_freq();

    // softmax over 16 profiles for this (b,v,f)
    float w[NPROF];
    float m = -INFINITY;
#pragma unroll
    for (int p = 0; p < NPROF; ++p) {
        w[p] = harm[((size_t)b * (NVOICE * NPROF) + v * NPROF + p) * NFRAME + f];
        m = fmaxf(m, w[p]);
    }
    float s = 0.0f;
#pragma unroll
    for (int p = 0; p < NPROF; ++p) { w[p] = expf(w[p] - m); s += w[p]; }
    const float inv = 1.0f / s;
#pragma unroll
    for (int p = 0; p < NPROF; ++p) w[p] *= inv;

    __syncthreads();   // profl ready

    const int rowbase = v * NKEEP;
    float* Fo = Fws + ((size_t)b * NFRAME + f) * NROWS2 + rowbase;
    float* Ao = Aws + ((size_t)b * NFRAME + f) * NROWS2 + rowbase;

    // row 0: fundamental (never clipped)
    Fo[0] = 0.5f * base; Ao[0] = amp0; Fl[0][f] = base;

    // rows 1..15: harmonics; ratio = (h+1)^2
#pragma unroll
    for (int h = 1; h < NKEEP; ++h) {
        const float r  = (float)((h + 1) * (h + 1));
        const float Fv = fminf(base * r, 1.0f);
        float ha = 0.0f;
#pragma unroll
        for (int p = 0; p < NPROF; ++p) ha = fmaf(w[p], profl[p][h - 1], ha);
        ha = fminf(fmaxf(ha, 0.0f), 1.0f) * amp0;
        Fo[h] = 0.5f * Fv; Ao[h] = ha; Fl[h][f] = Fv;
    }
    __syncthreads();

    // prefix pass (halved units): p2_0 = 64*F_0; p2_k = p2_{k-1} + 64*(F_{k-1}+F_k)
    if (f < NKEEP) {
        const int h = f;
        double p = 64.0 * (double)Fl[h][0];
        Pws[((size_t)b * NFRAME + 0) * NROWS2 + rowbase + h] = (float)(p - floor(p));
        float prev = Fl[h][0];
        for (int k = 1; k < NFRAME; ++k) {
            const float cur = Fl[h][k];
            p += 64.0 * ((double)prev + (double)cur);
            Pws[((size_t)b * NFRAME + k) * NROWS2 + rowbase + h] = (float)(p - floor(p));
            prev = cur;
        }
    }
}

// ---------------------------------------------------------------------------
// Phase B: one block per (batch, 256-sample chunk). Thread = one sample.
// Low half (tid<128) lies in segment c-1, high half in segment c.
//   S/2 = P2_k + t1*F2_k + t2*(F2_{k+1}-F2_k),  t1=j+1, t2=(j+1)^2/512
//   fa  = A_k + t3*(A_{k+1}-A_k),               t3=(j+0.5)/256
// sin(pi*S) = v_sin_f32(fract(S/2))   [v_sin takes revolutions]
// ---------------------------------------------------------------------------
__global__ __launch_bounds__(256)
void hm_phaseB(const float* __restrict__ Fws,
               const float* __restrict__ Aws,
               const float* __restrict__ Pws,
               float* __restrict__ out)
{
    const int blk = blockIdx.x;          // 0..1023
    const int b   = blk >> 6;
    const int c   = blk & 63;
    const int tid = threadIdx.x;

    __shared__ float4 lo4[NROWS2], hi4[NROWS2];   // {F2, dF2, A, dA}
    __shared__ float  plo[NROWS2], phi[NROWS2];

    const int fm1 = (c > 0)  ? c - 1 : 0;
    const int fp1 = (c < 63) ? c + 1 : 63;
    const float* Fb = Fws + (size_t)b * NFRAME * NROWS2;
    const float* Ab = Aws + (size_t)b * NFRAME * NROWS2;
    const float* Pb = Pws + (size_t)b * NFRAME * NROWS2;

    if (tid < NROWS2) {
        const int r = tid;
        const float Fm = Fb[(size_t)fm1 * NROWS2 + r];
        const float Fc = Fb[(size_t)c   * NROWS2 + r];
        const float Fp = Fb[(size_t)fp1 * NROWS2 + r];
        const float Am = Ab[(size_t)fm1 * NROWS2 + r];
        const float Ac = Ab[(size_t)c   * NROWS2 + r];
        const float Ap = Ab[(size_t)fp1 * NROWS2 + r];
        lo4[r] = make_float4(Fm, Fc - Fm, Am, Ac - Am);
        hi4[r] = make_float4(Fc, Fp - Fc, Ac, Ap - Ac);
        plo[r] = (c == 0) ? 0.0f : Pb[(size_t)(c - 1) * NROWS2 + r];
        phi[r] = Pb[(size_t)c * NROWS2 + r];
    }
    __syncthreads();

    const bool low = (tid < 128);
    const int  j   = (tid + 128) & 255;       // in-segment sample index
    float t1 = (float)(j + 1);
    const float t2 = (float)((j + 1) * (j + 1)) * (1.0f / 512.0f);
    const float t3 = ((float)j + 0.5f) * (1.0f / 256.0f);
    if (c == 0  && low)  t1 = (float)(tid + 1);     // flat head: S=(i+1)*F0
    if (c == 63 && !low) t1 = (float)(tid - 127);   // flat tail

    const float4* V = low ? lo4 : hi4;
    const float*  P = low ? plo : phi;

    float acc[4] = {0.0f, 0.0f, 0.0f, 0.0f};
#pragma unroll 4
    for (int r = 0; r < NROWS2; r += 4) {
#pragma unroll
        for (int u = 0; u < 4; ++u) {
            const float4 vv = V[r + u];
            const float x  = fmaf(t2, vv.y, fmaf(t1, vv.x, P[r + u]));
            const float fr = x - floorf(x);               // (S/2) mod 1
            const float fa = fmaf(t3, vv.w, vv.z);
            acc[u] = fmaf(fa, __builtin_amdgcn_sinf(fr), acc[u]);
        }
    }

    out[(size_t)b * NSAMP + c * 256 + tid] = (acc[0] + acc[1]) + (acc[2] + acc[3]);
}

// ---------------------------------------------------------------------------
extern "C" void kernel_launch(void* const* d_in, const int* in_sizes, int n_in,
                              void* d_out, int out_size, void* d_ws, size_t ws_size,
                              hipStream_t stream)
{
    const float* f0   = (const float*)d_in[0];   // (16, 16, 64)
    const float* harm = (const float*)d_in[1];   // (16, 128, 64)
    const float* prof = (const float*)d_in[2];   // (16, 64)

    const size_t plane = (size_t)NB * NFRAME * NROWS2;   // 131072 floats
    float* Fws = (float*)d_ws;
    float* Aws = Fws + plane;
    float* Pws = Aws + plane;

    hm_phaseA<<<NB * NVOICE, 64, 0, stream>>>(f0, harm, prof, Fws, Aws, Pws);
    hm_phaseB<<<NB * (NSAMP / 256), 256, 0, stream>>>(Fws, Aws, Pws, (float*)d_out);
}